// Round 9
// baseline (288.314 us; speedup 1.0000x reference)
//
#include <hip/hip_runtime.h>
#include <math.h>

#define VOCAB 20000
#define E     300
#define EP    320          // padded K for proj GEMM (10 k-steps of 32)
#define AP    328          // a_gat row pitch (656B -> 2-way-max LDS banks)
#define H     1024
#define G     8
#define NOUT  300
#define NP    320          // padded N for outproj
#define KOUT  8192         // G*H
#define NANS  4000
#define B     64
#define NQ    32
#define NK    256

typedef __attribute__((ext_vector_type(8))) short bf16x8;
typedef __attribute__((ext_vector_type(4))) float f32x4;

__device__ inline ushort f2bf(float x) {
    union { float f; unsigned u; } c; c.f = x;
    unsigned r = c.u + 0x7FFF + ((c.u >> 16) & 1);   // RNE
    return (ushort)(r >> 16);
}
__device__ inline float bf2f(ushort x) {
    union { unsigned u; float f; } c; c.u = ((unsigned)x) << 16;
    return c.f;
}
#define MFMA(a, b, c) __builtin_amdgcn_mfma_f32_16x16x32_bf16((a), (b), (c), 0, 0, 0)

// ---------------------------------------------------------------------------
// P00: emb_bf[v][320] bf16 from emb[v][300] f32. grid 313 x 256
// ---------------------------------------------------------------------------
__global__ __launch_bounds__(256) void prep_emb(
    const float* __restrict__ emb, ushort* __restrict__ emb_bf)
{
    const int r0 = blockIdx.x * 64;
    for (int i = threadIdx.x; i < 64 * 80; i += 256) {
        int r = r0 + (i / 80), c = i % 80;
        if (r >= VOCAB) break;
        ushort4 o{0, 0, 0, 0};
        if (c < 75) {
            float4 v = *(const float4*)(emb + (long)r * E + c * 4);
            o.x = f2bf(v.x); o.y = f2bf(v.y); o.z = f2bf(v.z); o.w = f2bf(v.w);
        }
        *(ushort4*)(emb_bf + (long)r * EP + c * 4) = o;
    }
}

// ---------------------------------------------------------------------------
// P0: WT[h][e] (bf16, e padded to 320) from W[e][h] f32.  grid (16, 2)
// ---------------------------------------------------------------------------
__global__ __launch_bounds__(256) void prep_wt(
    const float* __restrict__ Wq, const float* __restrict__ Wk,
    ushort* __restrict__ WTq, ushort* __restrict__ WTk)
{
    const float* W = blockIdx.y ? Wk : Wq;
    ushort* WT = blockIdx.y ? WTk : WTq;
    const int h0 = blockIdx.x * 64;
    __shared__ ushort lds[64][EP + 8];
    for (int i = threadIdx.x; i < 64 * EP; i += 256) {
        int e = i / 64, hh = i % 64;                 // coalesced along h
        float v = (e < E) ? W[e * H + h0 + hh] : 0.f;
        lds[hh][e] = f2bf(v);
    }
    __syncthreads();
    for (int i = threadIdx.x; i < 64 * EP; i += 256) {
        int hh = i / EP, e = i % EP;                 // coalesced along e
        WT[(h0 + hh) * EP + e] = lds[hh][e];
    }
}

// ---------------------------------------------------------------------------
// P0b: woutT[n][k] bf16 (n padded to 320) from Wout[k][n] f32. grid (128, 5)
// ---------------------------------------------------------------------------
__global__ __launch_bounds__(256) void prep_woutT(
    const float* __restrict__ Wout, ushort* __restrict__ woutT)
{
    const int k0 = blockIdx.x * 64, n0 = blockIdx.y * 64;
    __shared__ ushort td[64][72];
    for (int i = threadIdx.x; i < 64 * 64; i += 256) {
        int kk = i >> 6, nn = i & 63;
        int n = n0 + nn;
        float v = (n < NOUT) ? Wout[(k0 + kk) * NOUT + n] : 0.f;
        td[nn][kk] = f2bf(v);
    }
    __syncthreads();
    for (int i = threadIdx.x; i < 64 * 8; i += 256) {
        int nn = i >> 3, c = i & 7;
        *(bf16x8*)(woutT + (n0 + nn) * KOUT + k0 + c * 8) =
            *(const bf16x8*)(&td[nn][c * 8]);
    }
}

// ---------------------------------------------------------------------------
// P1q: hq_bf = emb_bf[he_q] @ Wq + bq   grid (64, 4) x 256 thr
// ---------------------------------------------------------------------------
__global__ __launch_bounds__(256) void proj_q_mfma(
    const int* __restrict__ idx, const ushort* __restrict__ emb_bf,
    const ushort* __restrict__ WT, const float* __restrict__ bias,
    ushort* __restrict__ out_bf16)
{
    __shared__ ushort sh[32 * 328];                  // 20,992 B (aliased phases)
    const int r0 = blockIdx.x * 32;
    const int n0 = blockIdx.y * 256;
    const int t = threadIdx.x;

    for (int i = t; i < 32 * 80; i += 256) {
        int r = i / 80, e4 = i % 80;
        *(ushort4*)(sh + r * 328 + e4 * 4) =
            *(const ushort4*)(emb_bf + (long)idx[r0 + r] * EP + e4 * 4);
    }
    __syncthreads();

    const int w = t >> 6, l = t & 63, lr = l & 15, lc = l >> 4;
    f32x4 acc[2][4] = {};
    const ushort* wtp = WT + (n0 + w * 64 + lr) * EP + lc * 8;
    const ushort* ap  = sh + lr * 328 + lc * 8;

    #pragma unroll 2
    for (int kk = 0; kk < 10; ++kk) {
        bf16x8 a0 = *(const bf16x8*)(ap + kk * 32);
        bf16x8 a1 = *(const bf16x8*)(ap + 16 * 328 + kk * 32);
        #pragma unroll
        for (int nt = 0; nt < 4; ++nt) {
            bf16x8 bfr = *(const bf16x8*)(wtp + nt * 16 * EP + kk * 32);
            acc[0][nt] = MFMA(a0, bfr, acc[0][nt]);
            acc[1][nt] = MFMA(a1, bfr, acc[1][nt]);
        }
    }
    __syncthreads();                                 // done reading A

    #pragma unroll
    for (int mt = 0; mt < 2; ++mt)
    #pragma unroll
    for (int nt = 0; nt < 4; ++nt) {
        const int col = w * 64 + nt * 16 + lr;
        const float bv = bias[n0 + col];
        #pragma unroll
        for (int r = 0; r < 4; ++r)
            sh[(mt * 16 + lc * 4 + r) * 264 + col] = f2bf(acc[mt][nt][r] + bv);
    }
    __syncthreads();
    for (int c = t; c < 1024; c += 256) {            // 32 q x 32 chunks(16B)
        int q = c >> 5, dc = c & 31;
        *(bf16x8*)(out_bf16 + (r0 + q) * H + n0 + dc * 8) =
            *(const bf16x8*)(sh + q * 264 + dc * 8);
    }
}

// ---------------------------------------------------------------------------
// P1g: a_gat[r][328] = emb_bf[he_kg[r]][0:320]   grid 1024 x 256 (16 rows/blk)
//      isolates the random gather from the GEMM
// ---------------------------------------------------------------------------
__global__ __launch_bounds__(256) void gather_k(
    const int* __restrict__ idx, const ushort* __restrict__ emb_bf,
    ushort* __restrict__ a_gat)
{
    const int r0 = blockIdx.x * 16;
    for (int i = threadIdx.x; i < 16 * 80; i += 256) {
        int r = i / 80, c = i % 80;
        *(ushort4*)(a_gat + (long)(r0 + r) * AP + c * 4) =
            *(const ushort4*)(emb_bf + (long)idx[r0 + r] * EP + c * 4);
    }
}

// ---------------------------------------------------------------------------
// P1k: hk_bf[b,k,d] = a_gat @ Wk + bk   grid (512, 2) x 512 thr
//      IDENTICAL structure to round-8 proj_k, but A is contiguous (no gather)
// ---------------------------------------------------------------------------
__global__ __launch_bounds__(512) void gemm_k(
    const ushort* __restrict__ a_gat, const ushort* __restrict__ WT,
    const float* __restrict__ bias, ushort* __restrict__ hk_bf)
{
    __shared__ ushort sh[32 * 520];                  // 33,280 B (aliased phases)
    const int r0 = blockIdx.x * 32;
    const int n0 = blockIdx.y * 512;
    const int t = threadIdx.x;

    for (int i = t; i < 32 * 80; i += 512) {
        int r = i / 80, e4 = i % 80;
        *(ushort4*)(sh + r * 328 + e4 * 4) =
            *(const ushort4*)(a_gat + (long)(r0 + r) * AP + e4 * 4);
    }
    __syncthreads();

    const int w = t >> 6, l = t & 63, lr = l & 15, lc = l >> 4;
    f32x4 acc[2][4] = {};
    const ushort* wtp = WT + (n0 + w * 64 + lr) * EP + lc * 8;
    const ushort* ap  = sh + lr * 328 + lc * 8;

    #pragma unroll 2
    for (int kk = 0; kk < 10; ++kk) {
        bf16x8 a0 = *(const bf16x8*)(ap + kk * 32);
        bf16x8 a1 = *(const bf16x8*)(ap + 16 * 328 + kk * 32);
        #pragma unroll
        for (int nt = 0; nt < 4; ++nt) {
            bf16x8 bfr = *(const bf16x8*)(wtp + nt * 16 * EP + kk * 32);
            acc[0][nt] = MFMA(a0, bfr, acc[0][nt]);
            acc[1][nt] = MFMA(a1, bfr, acc[1][nt]);
        }
    }
    __syncthreads();                                 // done reading A

    #pragma unroll
    for (int mt = 0; mt < 2; ++mt)
    #pragma unroll
    for (int nt = 0; nt < 4; ++nt) {
        const int col = w * 64 + nt * 16 + lr;       // 0..511 in tile
        const float bv = bias[n0 + col];
        #pragma unroll
        for (int r = 0; r < 4; ++r)
            sh[(mt * 16 + lc * 4 + r) * 520 + col] = f2bf(acc[mt][nt][r] + bv);
    }
    __syncthreads();

    for (int c = t; c < 2048; c += 512) {            // 32 k x 64 chunks(16B)
        int k = c >> 6, dc = c & 63;
        *(bf16x8*)(hk_bf + (r0 + k) * H + n0 + dc * 8) =
            *(const bf16x8*)(sh + k * 520 + dc * 8);
    }
}

// ---------------------------------------------------------------------------
// P1t: hkT[b][d][k] from hk_bf[b][k][d].  grid (64 b, 8 dt) x 256
// ---------------------------------------------------------------------------
__global__ __launch_bounds__(256) void transpose_hk(
    const ushort* __restrict__ hk_bf, ushort* __restrict__ hkT)
{
    __shared__ ushort td[256][136];                  // 69,632 B, k-major
    const int b = blockIdx.x, d0 = blockIdx.y * 128;
    const int t = threadIdx.x;

    for (int i = t; i < 256 * 16; i += 256) {        // [256 k][128 d] tile
        int k = i >> 4, dc = i & 15;
        *(bf16x8*)(&td[k][dc * 8]) =
            *(const bf16x8*)(hk_bf + (b * NK + k) * H + d0 + dc * 8);
    }
    __syncthreads();
    for (int i = t; i < 128 * 32; i += 256) {        // 128 d-rows x 32 chunks
        int d = i >> 5, c = i & 31;
        ushort tmp[8];
        #pragma unroll
        for (int j = 0; j < 8; ++j) tmp[j] = td[c * 8 + j][d];
        *(bf16x8*)(hkT + b * (H * NK) + (d0 + d) * NK + c * 8) =
            *(const bf16x8*)(tmp);
    }
}

// ---------------------------------------------------------------------------
// P2+P3 fused: att[b,g,q,k] = softmax_joint( (hq*watt_g) @ hk^T + batt[g] )
// ---------------------------------------------------------------------------
__global__ __launch_bounds__(256) void attn_mfma(
    const ushort* __restrict__ hq, const ushort* __restrict__ hk,
    const float* __restrict__ watt, const float* __restrict__ batt,
    ushort* __restrict__ att)
{
    const int b = blockIdx.x, g = blockIdx.y;
    const int t = threadIdx.x, w = t >> 6, l = t & 63, lr = l & 15, lc = l >> 4;
    __shared__ float wg[H];
    __shared__ float red[8];

    for (int i = t; i < H; i += 256) wg[i] = watt[i * G + g];
    __syncthreads();

    const ushort* ap = hq + (b * NQ + lr) * H + lc * 8;
    const ushort* bp = hk + (b * NK + w * 64 + lr) * H + lc * 8;
    f32x4 acc[2][4] = {};

    #pragma unroll 2
    for (int kk = 0; kk < 32; ++kk) {
        const int d0 = kk * 32 + lc * 8;
        bf16x8 h0 = *(const bf16x8*)(ap + kk * 32);
        bf16x8 h1 = *(const bf16x8*)(ap + 16 * H + kk * 32);
        f32x4 w0 = *(const f32x4*)(&wg[d0]);
        f32x4 w1 = *(const f32x4*)(&wg[d0 + 4]);
        bf16x8 a0, a1;
        #pragma unroll
        for (int j = 0; j < 4; ++j) {
            a0[j]     = (short)f2bf(bf2f((ushort)h0[j]) * w0[j]);
            a0[j + 4] = (short)f2bf(bf2f((ushort)h0[j + 4]) * w1[j]);
            a1[j]     = (short)f2bf(bf2f((ushort)h1[j]) * w0[j]);
            a1[j + 4] = (short)f2bf(bf2f((ushort)h1[j + 4]) * w1[j]);
        }
        #pragma unroll
        for (int nt = 0; nt < 4; ++nt) {
            bf16x8 bfr = *(const bf16x8*)(bp + nt * 16 * H + kk * 32);
            acc[0][nt] = MFMA(a0, bfr, acc[0][nt]);
            acc[1][nt] = MFMA(a1, bfr, acc[1][nt]);
        }
    }

    const float bg = batt[g];
    float lm = -1e30f;
    #pragma unroll
    for (int mt = 0; mt < 2; ++mt)
    #pragma unroll
    for (int nt = 0; nt < 4; ++nt)
    #pragma unroll
    for (int r = 0; r < 4; ++r) {
        acc[mt][nt][r] += bg;
        lm = fmaxf(lm, acc[mt][nt][r]);
    }
    #pragma unroll
    for (int off = 32; off; off >>= 1) lm = fmaxf(lm, __shfl_xor(lm, off));
    if (l == 0) red[w] = lm;
    __syncthreads();
    const float gm = fmaxf(fmaxf(red[0], red[1]), fmaxf(red[2], red[3]));

    float ls = 0.f;
    #pragma unroll
    for (int mt = 0; mt < 2; ++mt)
    #pragma unroll
    for (int nt = 0; nt < 4; ++nt)
    #pragma unroll
    for (int r = 0; r < 4; ++r) {
        float e = __expf(acc[mt][nt][r] - gm);
        acc[mt][nt][r] = e;
        ls += e;
    }
    #pragma unroll
    for (int off = 32; off; off >>= 1) ls += __shfl_xor(ls, off);
    if (l == 0) red[4 + w] = ls;
    __syncthreads();
    const float inv = 1.f / (red[4] + red[5] + red[6] + red[7]);

    ushort* op = att + (b * 8 + g) * (NQ * NK);
    #pragma unroll
    for (int mt = 0; mt < 2; ++mt)
    #pragma unroll
    for (int nt = 0; nt < 4; ++nt)
    #pragma unroll
    for (int r = 0; r < 4; ++r)
        op[(mt * 16 + lc * 4 + r) * NK + w * 64 + nt * 16 + lr] =
            f2bf(acc[mt][nt][r] * inv);
}

// ---------------------------------------------------------------------------
// P4: ctx = att[b,g] @ hkT[b], pooled_bf[b,g,d] = bf16(sum_q hq*ctx)
// ---------------------------------------------------------------------------
__global__ __launch_bounds__(256) void pooled_mfma(
    const ushort* __restrict__ att, const ushort* __restrict__ hkT,
    const ushort* __restrict__ hq, ushort* __restrict__ pooled_bf)
{
    const int b = blockIdx.x, g = blockIdx.y;
    const int t = threadIdx.x, w = t >> 6, l = t & 63, lr = l & 15, lc = l >> 4;
    const ushort* ap = att + ((b * 8 + g) * 32 + lr) * NK + lc * 8;
    const ushort* bp = hkT + b * (H * NK) + (w * 256 + lr) * NK + lc * 8;
    f32x4 acc[2][16] = {};

    #pragma unroll 2
    for (int kk = 0; kk < 8; ++kk) {
        bf16x8 a0 = *(const bf16x8*)(ap + kk * 32);
        bf16x8 a1 = *(const bf16x8*)(ap + 16 * NK + kk * 32);
        #pragma unroll
        for (int nt = 0; nt < 16; ++nt) {
            bf16x8 bfr = *(const bf16x8*)(bp + nt * 16 * NK + kk * 32);
            acc[0][nt] = MFMA(a0, bfr, acc[0][nt]);
            acc[1][nt] = MFMA(a1, bfr, acc[1][nt]);
        }
    }

    const ushort* hqb = hq + b * NQ * H;
    #pragma unroll
    for (int nt = 0; nt < 16; ++nt) {
        const int d = w * 256 + nt * 16 + lr;
        float s = 0.f;
        #pragma unroll
        for (int mt = 0; mt < 2; ++mt) {
            const int q = mt * 16 + lc * 4;
            #pragma unroll
            for (int r = 0; r < 4; ++r)
                s += bf2f(hqb[(q + r) * H + d]) * acc[mt][nt][r];
        }
        s += __shfl_xor(s, 16);
        s += __shfl_xor(s, 32);
        if (l < 16) pooled_bf[(b * 8 + g) * H + d] = f2bf(s);
    }
}

// ---------------------------------------------------------------------------
// P5: out = pooled_bf[64,8192] @ woutT^T  (MFMA, 64-way k-split)
// ---------------------------------------------------------------------------
__global__ __launch_bounds__(256) void outproj_mfma(
    const ushort* __restrict__ pooled_bf, const ushort* __restrict__ woutT,
    float* __restrict__ partial)
{
    const int ks = blockIdx.x;
    const int k0 = ks * 128;
    const int t = threadIdx.x, w = t >> 6, l = t & 63, lr = l & 15, lc = l >> 4;
    const ushort* ap = pooled_bf + lr * KOUT + k0 + lc * 8;
    const ushort* bp = woutT + (w * 80 + lr) * KOUT + k0 + lc * 8;
    f32x4 acc[4][5] = {};

    #pragma unroll
    for (int kk = 0; kk < 4; ++kk) {
        bf16x8 a[4];
        #pragma unroll
        for (int mt = 0; mt < 4; ++mt)
            a[mt] = *(const bf16x8*)(ap + mt * 16 * KOUT + kk * 32);
        #pragma unroll
        for (int nt = 0; nt < 5; ++nt) {
            bf16x8 bfr = *(const bf16x8*)(bp + nt * 16 * KOUT + kk * 32);
            #pragma unroll
            for (int mt = 0; mt < 4; ++mt)
                acc[mt][nt] = MFMA(a[mt], bfr, acc[mt][nt]);
        }
    }

    #pragma unroll
    for (int mt = 0; mt < 4; ++mt)
    #pragma unroll
    for (int nt = 0; nt < 5; ++nt)
    #pragma unroll
    for (int r = 0; r < 4; ++r) {
        const int bb = mt * 16 + lc * 4 + r;
        const int n = w * 80 + nt * 16 + lr;
        partial[(ks * B + bb) * NP + n] = acc[mt][nt][r];
    }
}

// ---------------------------------------------------------------------------
// P6: outv[b,n] = bout[n] + sum_ks partial[ks,b,n]   (76 blocks x 256)
// ---------------------------------------------------------------------------
__global__ __launch_bounds__(256) void reduce_out_kernel(
    const float* __restrict__ partial, const float* __restrict__ bout,
    float* __restrict__ outv)
{
    const int i = blockIdx.x * 256 + threadIdx.x;   // 64*304
    if (i >= B * 304) return;
    const int b = i / 304, n = i % 304;
    float acc = 0.f;
    if (n < NOUT) {
        acc = bout[n];
        for (int ks = 0; ks < 64; ++ks)
            acc += partial[(ks * B + b) * NP + n];
    }
    outv[b * 304 + n] = acc;
}

// ---------------------------------------------------------------------------
// S1: sim[b,a] = outv[b]·glove[a]  — 250 blocks x (16 answers x 64 b)
// ---------------------------------------------------------------------------
__global__ __launch_bounds__(256) void sim_kernel(
    const float* __restrict__ outv, const float* __restrict__ glove,
    float* __restrict__ sim)
{
    __shared__ __align__(16) float ov[64][308];
    __shared__ __align__(16) float gl[16][308];
    const int t = threadIdx.x;
    const int a0 = blockIdx.x * 16;

    for (int i = t; i < 64 * 75; i += 256) {
        int r = i / 75, c = i % 75;
        *(float4*)(&ov[r][c * 4]) = *(const float4*)(&outv[r * 304 + c * 4]);
    }
    for (int i = t; i < 16 * 75; i += 256) {
        int r = i / 75, c = i % 75;
        *(float4*)(&gl[r][c * 4]) = *(const float4*)(&glove[(a0 + r) * NOUT + c * 4]);
    }
    __syncthreads();

    const int a = t & 15, bg = t >> 4;   // 16 answers x 16 b-groups(4 b each)
    float acc[4] = {};
    for (int k4 = 0; k4 < 75; ++k4) {
        float4 g = *(const float4*)(&gl[a][k4 * 4]);
        #pragma unroll
        for (int bi = 0; bi < 4; ++bi) {
            float4 o = *(const float4*)(&ov[bg * 4 + bi][k4 * 4]);
            acc[bi] += g.x * o.x + g.y * o.y + g.z * o.z + g.w * o.w;
        }
    }
    #pragma unroll
    for (int bi = 0; bi < 4; ++bi)
        sim[(bg * 4 + bi) * NANS + a0 + a] = acc[bi];
}

// ---------------------------------------------------------------------------
// S2: per-b log_softmax over 4000, write d_out
// ---------------------------------------------------------------------------
__global__ __launch_bounds__(256) void lsm_kernel(
    const float* __restrict__ sim, float* __restrict__ dout)
{
    const int b = blockIdx.x, t = threadIdx.x;
    const float* p = sim + b * NANS;
    __shared__ float red[4];

    float4 v[4];
    float lm = -1e30f;
    #pragma unroll
    for (int j = 0; j < 4; ++j) {
        int i = t + j * 256;
        if (i < 1000) {
            v[j] = ((const float4*)p)[i];
            lm = fmaxf(lm, fmaxf(fmaxf(v[j].x, v[j].y), fmaxf(v[j].z, v[j].w)));
        }
    }
    #pragma unroll
    for (int off = 32; off; off >>= 1) lm = fmaxf(lm, __shfl_xor(lm, off));
    if ((t & 63) == 0) red[t >> 6] = lm;
    __syncthreads();
    const float gm = fmaxf(fmaxf(red[0], red[1]), fmaxf(red[2], red[3]));

    float ls = 0.f;
    #pragma unroll
    for (int j = 0; j < 4; ++j) {
        int i = t + j * 256;
        if (i < 1000)
            ls += __expf(v[j].x - gm) + __expf(v[j].y - gm) +
                  __expf(v[j].z - gm) + __expf(v[j].w - gm);
    }
    #pragma unroll
    for (int off = 32; off; off >>= 1) ls += __shfl_xor(ls, off);
    __syncthreads();
    if ((t & 63) == 0) red[t >> 6] = ls;
    __syncthreads();
    const float sh = gm + logf(red[0] + red[1] + red[2] + red[3]);

    #pragma unroll
    for (int j = 0; j < 4; ++j) {
        int i = t + j * 256;
        if (i < 1000) {
            float4 o;
            o.x = v[j].x - sh; o.y = v[j].y - sh;
            o.z = v[j].z - sh; o.w = v[j].w - sh;
            ((float4*)(dout + b * NANS))[i] = o;
        }
    }
}

// ---------------------------------------------------------------------------
extern "C" void kernel_launch(void* const* d_in, const int* in_sizes, int n_in,
                              void* d_out, int out_size, void* d_ws, size_t ws_size,
                              hipStream_t stream)
{
    (void)in_sizes; (void)n_in; (void)out_size; (void)ws_size;
    const int*   he_q  = (const int*)  d_in[0];
    const int*   he_k  = (const int*)  d_in[1];
    const float* emb   = (const float*)d_in[2];
    const float* Wq    = (const float*)d_in[3];
    const float* bq    = (const float*)d_in[4];
    const float* Wk    = (const float*)d_in[5];
    const float* bk    = (const float*)d_in[6];
    const float* Watt  = (const float*)d_in[7];
    const float* batt  = (const float*)d_in[8];
    const float* Wout  = (const float*)d_in[9];
    const float* bout  = (const float*)d_in[10];
    const float* glove = (const float*)d_in[11];
    float* out = (float*)d_out;

    ushort* WTq    = (ushort*)d_ws;                  //    327,680 sh
    ushort* WTk    = WTq + 327680;                   //    327,680 sh
    ushort* emb_bf = WTk + 327680;                   //  6,400,000 sh  [v][320]
    ushort* a_gat  = emb_bf + 6400000;               //  5,373,952 sh  [16384][328]
    ushort* hq_bf  = a_gat + 5373952;                //  2,097,152 sh  [b][q][d]
    ushort* hk_bf  = hq_bf + 2097152;                // 16,777,216 sh  [b][k][d]
    ushort* hkT    = hk_bf + 16777216;               // 16,777,216 sh  [b][d][k]
    ushort* pool_bf= hkT + 16777216;                 //    524,288 sh  [b][g*H+d]
    ushort* woutT  = pool_bf + 524288;               //  2,621,440 sh  [320][8192]
    ushort* att    = woutT + 2621440;                //  4,194,304 sh
    float*  partial= (float*)(att + 4194304);        //  1,310,720 f32 [64][64][320]
    float*  outv   = partial + 1310720;              //     19,456 f32
    float*  sim    = outv + 19456;                   //    256,000 f32

    prep_emb<<<dim3(313), 256, 0, stream>>>(emb, emb_bf);
    prep_wt<<<dim3(16, 2), 256, 0, stream>>>(Wq, Wk, WTq, WTk);
    prep_woutT<<<dim3(128, 5), 256, 0, stream>>>(Wout, woutT);
    proj_q_mfma<<<dim3(64, 4), 256, 0, stream>>>(he_q, emb_bf, WTq, bq, hq_bf);
    gather_k<<<dim3(1024), 256, 0, stream>>>(he_k, emb_bf, a_gat);
    gemm_k<<<dim3(512, 2), 512, 0, stream>>>(a_gat, WTk, bk, hk_bf);
    transpose_hk<<<dim3(64, 8), 256, 0, stream>>>(hk_bf, hkT);
    attn_mfma<<<dim3(64, 8), 256, 0, stream>>>(hq_bf, hk_bf, Watt, batt, att);
    pooled_mfma<<<dim3(64, 8), 256, 0, stream>>>(att, hkT, hq_bf, pool_bf);
    outproj_mfma<<<dim3(64), 256, 0, stream>>>(pool_bf, woutT, partial);
    reduce_out_kernel<<<dim3(76), 256, 0, stream>>>(partial, bout, outv);
    sim_kernel<<<dim3(250), 256, 0, stream>>>(outv, glove, sim);
    lsm_kernel<<<dim3(64), 256, 0, stream>>>(sim, out);
}

// Round 10
// 213.183 us; speedup vs baseline: 1.3524x; 1.3524x over previous
//
#include <hip/hip_runtime.h>
#include <math.h>

#define VOCAB 20000
#define E     300
#define EP    320          // padded K for proj GEMM (10 k-steps of 32)
#define H     1024
#define G     8
#define NOUT  300
#define NP    320          // padded N for outproj
#define KOUT  8192         // G*H
#define NANS  4000
#define B     64
#define NQ    32
#define NK    256

typedef __attribute__((ext_vector_type(8))) short bf16x8;
typedef __attribute__((ext_vector_type(4))) float f32x4;

__device__ inline ushort f2bf(float x) {
    union { float f; unsigned u; } c; c.f = x;
    unsigned r = c.u + 0x7FFF + ((c.u >> 16) & 1);   // RNE
    return (ushort)(r >> 16);
}
__device__ inline float bf2f(ushort x) {
    union { unsigned u; float f; } c; c.u = ((unsigned)x) << 16;
    return c.f;
}
#define MFMA(a, b, c) __builtin_amdgcn_mfma_f32_16x16x32_bf16((a), (b), (c), 0, 0, 0)

// ---------------------------------------------------------------------------
// P00: emb_bf[v][320] bf16 from emb[v][300] f32. grid 313 x 256
// ---------------------------------------------------------------------------
__global__ __launch_bounds__(256) void prep_emb(
    const float* __restrict__ emb, ushort* __restrict__ emb_bf)
{
    const int r0 = blockIdx.x * 64;
    for (int i = threadIdx.x; i < 64 * 80; i += 256) {
        int r = r0 + (i / 80), c = i % 80;
        if (r >= VOCAB) break;
        ushort4 o{0, 0, 0, 0};
        if (c < 75) {
            float4 v = *(const float4*)(emb + (long)r * E + c * 4);
            o.x = f2bf(v.x); o.y = f2bf(v.y); o.z = f2bf(v.z); o.w = f2bf(v.w);
        }
        *(ushort4*)(emb_bf + (long)r * EP + c * 4) = o;
    }
}

// ---------------------------------------------------------------------------
// P0: WT[h][e] (bf16, e padded to 320) from W[e][h] f32.  grid (16, 2)
// ---------------------------------------------------------------------------
__global__ __launch_bounds__(256) void prep_wt(
    const float* __restrict__ Wq, const float* __restrict__ Wk,
    ushort* __restrict__ WTq, ushort* __restrict__ WTk)
{
    const float* W = blockIdx.y ? Wk : Wq;
    ushort* WT = blockIdx.y ? WTk : WTq;
    const int h0 = blockIdx.x * 64;
    __shared__ ushort lds[64][EP + 8];
    for (int i = threadIdx.x; i < 64 * EP; i += 256) {
        int e = i / 64, hh = i % 64;                 // coalesced along h
        float v = (e < E) ? W[e * H + h0 + hh] : 0.f;
        lds[hh][e] = f2bf(v);
    }
    __syncthreads();
    for (int i = threadIdx.x; i < 64 * EP; i += 256) {
        int hh = i / EP, e = i % EP;                 // coalesced along e
        WT[(h0 + hh) * EP + e] = lds[hh][e];
    }
}

// ---------------------------------------------------------------------------
// P0b: woutT[n][k] bf16 (n padded to 320) from Wout[k][n] f32. grid (128, 5)
// ---------------------------------------------------------------------------
__global__ __launch_bounds__(256) void prep_woutT(
    const float* __restrict__ Wout, ushort* __restrict__ woutT)
{
    const int k0 = blockIdx.x * 64, n0 = blockIdx.y * 64;
    __shared__ ushort td[64][72];
    for (int i = threadIdx.x; i < 64 * 64; i += 256) {
        int kk = i >> 6, nn = i & 63;
        int n = n0 + nn;
        float v = (n < NOUT) ? Wout[(k0 + kk) * NOUT + n] : 0.f;
        td[nn][kk] = f2bf(v);
    }
    __syncthreads();
    for (int i = threadIdx.x; i < 64 * 8; i += 256) {
        int nn = i >> 3, c = i & 7;
        *(bf16x8*)(woutT + (n0 + nn) * KOUT + k0 + c * 8) =
            *(const bf16x8*)(&td[nn][c * 8]);
    }
}

// ---------------------------------------------------------------------------
// P1: gather-GEMM, 128x128 block tile, 4 waves (64x64/wave), BK=32 x 10 steps
//     out[r][d] = emb_bf[idx[r]] @ WT^T + bias   (row-major out)
//     WRITE_T=1: also write outT[b][d][k] (b=r0/256, k=r0%256..+127)
//     grid (Mtiles, 8) x 256
// ---------------------------------------------------------------------------
template <int WRITE_T>
__global__ __launch_bounds__(256, 2) void proj_big(
    const int* __restrict__ idx, const ushort* __restrict__ emb_bf,
    const ushort* __restrict__ WT, const float* __restrict__ bias,
    ushort* __restrict__ outr, ushort* __restrict__ outT)
{
    __shared__ ushort lds[128 * 130];                // 33,280 B (aliased)
    __shared__ int sidx[128];
    const int r0 = blockIdx.x * 128;
    const int n0 = blockIdx.y * 128;
    const int t = threadIdx.x;

    if (t < 128) sidx[t] = idx[r0 + t];

    const int w = t >> 6, l = t & 63, lr = l & 15, lc = l >> 4;
    const int wm = (w >> 1) * 64, wn = (w & 1) * 64;
    const int srow = t >> 2;                         // staging row (64/pass)
    const int scol = (t & 3) * 8;                    // staging elem offset
    ushort* As = lds;                                // [128][40]
    ushort* Bs = lds + 5120;                         // [128][40]
    f32x4 acc[4][4] = {};

    __syncthreads();                                 // sidx ready

    for (int kk = 0; kk < 10; ++kk) {
        if (kk) __syncthreads();                     // prev reads done
        #pragma unroll
        for (int p = 0; p < 2; ++p) {
            int r = p * 64 + srow;
            *(bf16x8*)(As + r * 40 + scol) =
                *(const bf16x8*)(emb_bf + (long)sidx[r] * EP + kk * 32 + scol);
            *(bf16x8*)(Bs + r * 40 + scol) =
                *(const bf16x8*)(WT + (long)(n0 + r) * EP + kk * 32 + scol);
        }
        __syncthreads();

        bf16x8 af[4], bf[4];
        #pragma unroll
        for (int mf = 0; mf < 4; ++mf)
            af[mf] = *(const bf16x8*)(As + (wm + mf * 16 + lr) * 40 + lc * 8);
        #pragma unroll
        for (int nf = 0; nf < 4; ++nf)
            bf[nf] = *(const bf16x8*)(Bs + (wn + nf * 16 + lr) * 40 + lc * 8);
        #pragma unroll
        for (int mf = 0; mf < 4; ++mf)
            #pragma unroll
            for (int nf = 0; nf < 4; ++nf)
                acc[mf][nf] = MFMA(af[mf], bf[nf], acc[mf][nf]);
    }
    __syncthreads();                                 // loop reads done

    // acc -> bias -> bf16 tile[128 row][130 pitch]
    #pragma unroll
    for (int mf = 0; mf < 4; ++mf)
    #pragma unroll
    for (int nf = 0; nf < 4; ++nf) {
        const int col = wn + nf * 16 + lr;
        const float bv = bias[n0 + col];
        #pragma unroll
        for (int r = 0; r < 4; ++r)
            lds[(wm + mf * 16 + lc * 4 + r) * 130 + col] =
                f2bf(acc[mf][nf][r] + bv);
    }
    __syncthreads();

    // row-major out: 128 rows x 16 chunks(16B) -> 256B contiguous per row
    for (int i = t; i < 128 * 16; i += 256) {
        int k = i >> 4, c = i & 15;
        *(bf16x8*)(outr + (long)(r0 + k) * H + n0 + c * 8) =
            *(const bf16x8*)(lds + k * 130 + c * 8);
    }
    if (WRITE_T) {
        const int b = r0 >> 8, k0 = r0 & 255;
        // transposed out: 128 d-rows x 16 chunks; column reads stride 65 words
        for (int i = t; i < 128 * 16; i += 256) {
            int d = i >> 4, c = i & 15;
            ushort tmp[8];
            #pragma unroll
            for (int j = 0; j < 8; ++j) tmp[j] = lds[(c * 8 + j) * 130 + d];
            *(bf16x8*)(outT + (long)b * (H * NK) + (n0 + d) * NK + k0 + c * 8) =
                *(const bf16x8*)(tmp);
        }
    }
}

// ---------------------------------------------------------------------------
// P2+P3 fused: att[b,g,q,k] = softmax_joint( (hq*watt_g) @ hk^T + batt[g] )
// ---------------------------------------------------------------------------
__global__ __launch_bounds__(256) void attn_mfma(
    const ushort* __restrict__ hq, const ushort* __restrict__ hk,
    const float* __restrict__ watt, const float* __restrict__ batt,
    ushort* __restrict__ att)
{
    const int b = blockIdx.x, g = blockIdx.y;
    const int t = threadIdx.x, w = t >> 6, l = t & 63, lr = l & 15, lc = l >> 4;
    __shared__ float wg[H];
    __shared__ float red[8];

    for (int i = t; i < H; i += 256) wg[i] = watt[i * G + g];
    __syncthreads();

    const ushort* ap = hq + (b * NQ + lr) * H + lc * 8;
    const ushort* bp = hk + (b * NK + w * 64 + lr) * H + lc * 8;
    f32x4 acc[2][4] = {};

    #pragma unroll 2
    for (int kk = 0; kk < 32; ++kk) {
        const int d0 = kk * 32 + lc * 8;
        bf16x8 h0 = *(const bf16x8*)(ap + kk * 32);
        bf16x8 h1 = *(const bf16x8*)(ap + 16 * H + kk * 32);
        f32x4 w0 = *(const f32x4*)(&wg[d0]);
        f32x4 w1 = *(const f32x4*)(&wg[d0 + 4]);
        bf16x8 a0, a1;
        #pragma unroll
        for (int j = 0; j < 4; ++j) {
            a0[j]     = (short)f2bf(bf2f((ushort)h0[j]) * w0[j]);
            a0[j + 4] = (short)f2bf(bf2f((ushort)h0[j + 4]) * w1[j]);
            a1[j]     = (short)f2bf(bf2f((ushort)h1[j]) * w0[j]);
            a1[j + 4] = (short)f2bf(bf2f((ushort)h1[j + 4]) * w1[j]);
        }
        #pragma unroll
        for (int nt = 0; nt < 4; ++nt) {
            bf16x8 bfr = *(const bf16x8*)(bp + nt * 16 * H + kk * 32);
            acc[0][nt] = MFMA(a0, bfr, acc[0][nt]);
            acc[1][nt] = MFMA(a1, bfr, acc[1][nt]);
        }
    }

    const float bg = batt[g];
    float lm = -1e30f;
    #pragma unroll
    for (int mt = 0; mt < 2; ++mt)
    #pragma unroll
    for (int nt = 0; nt < 4; ++nt)
    #pragma unroll
    for (int r = 0; r < 4; ++r) {
        acc[mt][nt][r] += bg;
        lm = fmaxf(lm, acc[mt][nt][r]);
    }
    #pragma unroll
    for (int off = 32; off; off >>= 1) lm = fmaxf(lm, __shfl_xor(lm, off));
    if (l == 0) red[w] = lm;
    __syncthreads();
    const float gm = fmaxf(fmaxf(red[0], red[1]), fmaxf(red[2], red[3]));

    float ls = 0.f;
    #pragma unroll
    for (int mt = 0; mt < 2; ++mt)
    #pragma unroll
    for (int nt = 0; nt < 4; ++nt)
    #pragma unroll
    for (int r = 0; r < 4; ++r) {
        float e = __expf(acc[mt][nt][r] - gm);
        acc[mt][nt][r] = e;
        ls += e;
    }
    #pragma unroll
    for (int off = 32; off; off >>= 1) ls += __shfl_xor(ls, off);
    if (l == 0) red[4 + w] = ls;
    __syncthreads();
    const float inv = 1.f / (red[4] + red[5] + red[6] + red[7]);

    ushort* op = att + (b * 8 + g) * (NQ * NK);
    #pragma unroll
    for (int mt = 0; mt < 2; ++mt)
    #pragma unroll
    for (int nt = 0; nt < 4; ++nt)
    #pragma unroll
    for (int r = 0; r < 4; ++r)
        op[(mt * 16 + lc * 4 + r) * NK + w * 64 + nt * 16 + lr] =
            f2bf(acc[mt][nt][r] * inv);
}

// ---------------------------------------------------------------------------
// P4: ctx = att[b,g] @ hkT[b], pooled_bf[b,g,d] = bf16(sum_q hq*ctx)
// ---------------------------------------------------------------------------
__global__ __launch_bounds__(256) void pooled_mfma(
    const ushort* __restrict__ att, const ushort* __restrict__ hkT,
    const ushort* __restrict__ hq, ushort* __restrict__ pooled_bf)
{
    const int b = blockIdx.x, g = blockIdx.y;
    const int t = threadIdx.x, w = t >> 6, l = t & 63, lr = l & 15, lc = l >> 4;
    const ushort* ap = att + ((b * 8 + g) * 32 + lr) * NK + lc * 8;
    const ushort* bp = hkT + b * (H * NK) + (w * 256 + lr) * NK + lc * 8;
    f32x4 acc[2][16] = {};

    #pragma unroll 2
    for (int kk = 0; kk < 8; ++kk) {
        bf16x8 a0 = *(const bf16x8*)(ap + kk * 32);
        bf16x8 a1 = *(const bf16x8*)(ap + 16 * NK + kk * 32);
        #pragma unroll
        for (int nt = 0; nt < 16; ++nt) {
            bf16x8 bfr = *(const bf16x8*)(bp + nt * 16 * NK + kk * 32);
            acc[0][nt] = MFMA(a0, bfr, acc[0][nt]);
            acc[1][nt] = MFMA(a1, bfr, acc[1][nt]);
        }
    }

    const ushort* hqb = hq + b * NQ * H;
    #pragma unroll
    for (int nt = 0; nt < 16; ++nt) {
        const int d = w * 256 + nt * 16 + lr;
        float s = 0.f;
        #pragma unroll
        for (int mt = 0; mt < 2; ++mt) {
            const int q = mt * 16 + lc * 4;
            #pragma unroll
            for (int r = 0; r < 4; ++r)
                s += bf2f(hqb[(q + r) * H + d]) * acc[mt][nt][r];
        }
        s += __shfl_xor(s, 16);
        s += __shfl_xor(s, 32);
        if (l < 16) pooled_bf[(b * 8 + g) * H + d] = f2bf(s);
    }
}

// ---------------------------------------------------------------------------
// P5: out = pooled_bf[64,8192] @ woutT^T  (MFMA, 64-way k-split)
// ---------------------------------------------------------------------------
__global__ __launch_bounds__(256) void outproj_mfma(
    const ushort* __restrict__ pooled_bf, const ushort* __restrict__ woutT,
    float* __restrict__ partial)
{
    const int ks = blockIdx.x;
    const int k0 = ks * 128;
    const int t = threadIdx.x, w = t >> 6, l = t & 63, lr = l & 15, lc = l >> 4;
    const ushort* ap = pooled_bf + lr * KOUT + k0 + lc * 8;
    const ushort* bp = woutT + (w * 80 + lr) * KOUT + k0 + lc * 8;
    f32x4 acc[4][5] = {};

    #pragma unroll
    for (int kk = 0; kk < 4; ++kk) {
        bf16x8 a[4];
        #pragma unroll
        for (int mt = 0; mt < 4; ++mt)
            a[mt] = *(const bf16x8*)(ap + mt * 16 * KOUT + kk * 32);
        #pragma unroll
        for (int nt = 0; nt < 5; ++nt) {
            bf16x8 bfr = *(const bf16x8*)(bp + nt * 16 * KOUT + kk * 32);
            #pragma unroll
            for (int mt = 0; mt < 4; ++mt)
                acc[mt][nt] = MFMA(a[mt], bfr, acc[mt][nt]);
        }
    }

    #pragma unroll
    for (int mt = 0; mt < 4; ++mt)
    #pragma unroll
    for (int nt = 0; nt < 5; ++nt)
    #pragma unroll
    for (int r = 0; r < 4; ++r) {
        const int bb = mt * 16 + lc * 4 + r;
        const int n = w * 80 + nt * 16 + lr;
        partial[(ks * B + bb) * NP + n] = acc[mt][nt][r];
    }
}

// ---------------------------------------------------------------------------
// P6: outv[b,n] = bout[n] + sum_ks partial[ks,b,n]   (76 blocks x 256)
// ---------------------------------------------------------------------------
__global__ __launch_bounds__(256) void reduce_out_kernel(
    const float* __restrict__ partial, const float* __restrict__ bout,
    float* __restrict__ outv)
{
    const int i = blockIdx.x * 256 + threadIdx.x;   // 64*304
    if (i >= B * 304) return;
    const int b = i / 304, n = i % 304;
    float acc = 0.f;
    if (n < NOUT) {
        acc = bout[n];
        for (int ks = 0; ks < 64; ++ks)
            acc += partial[(ks * B + b) * NP + n];
    }
    outv[b * 304 + n] = acc;
}

// ---------------------------------------------------------------------------
// S1: sim[b,a] = outv[b]·glove[a]  — 250 blocks x (16 answers x 64 b)
// ---------------------------------------------------------------------------
__global__ __launch_bounds__(256) void sim_kernel(
    const float* __restrict__ outv, const float* __restrict__ glove,
    float* __restrict__ sim)
{
    __shared__ __align__(16) float ov[64][308];
    __shared__ __align__(16) float gl[16][308];
    const int t = threadIdx.x;
    const int a0 = blockIdx.x * 16;

    for (int i = t; i < 64 * 75; i += 256) {
        int r = i / 75, c = i % 75;
        *(float4*)(&ov[r][c * 4]) = *(const float4*)(&outv[r * 304 + c * 4]);
    }
    for (int i = t; i < 16 * 75; i += 256) {
        int r = i / 75, c = i % 75;
        *(float4*)(&gl[r][c * 4]) = *(const float4*)(&glove[(a0 + r) * NOUT + c * 4]);
    }
    __syncthreads();

    const int a = t & 15, bg = t >> 4;   // 16 answers x 16 b-groups(4 b each)
    float acc[4] = {};
    for (int k4 = 0; k4 < 75; ++k4) {
        float4 g = *(const float4*)(&gl[a][k4 * 4]);
        #pragma unroll
        for (int bi = 0; bi < 4; ++bi) {
            float4 o = *(const float4*)(&ov[bg * 4 + bi][k4 * 4]);
            acc[bi] += g.x * o.x + g.y * o.y + g.z * o.z + g.w * o.w;
        }
    }
    #pragma unroll
    for (int bi = 0; bi < 4; ++bi)
        sim[(bg * 4 + bi) * NANS + a0 + a] = acc[bi];
}

// ---------------------------------------------------------------------------
// S2: per-b log_softmax over 4000, write d_out
// ---------------------------------------------------------------------------
__global__ __launch_bounds__(256) void lsm_kernel(
    const float* __restrict__ sim, float* __restrict__ dout)
{
    const int b = blockIdx.x, t = threadIdx.x;
    const float* p = sim + b * NANS;
    __shared__ float red[4];

    float4 v[4];
    float lm = -1e30f;
    #pragma unroll
    for (int j = 0; j < 4; ++j) {
        int i = t + j * 256;
        if (i < 1000) {
            v[j] = ((const float4*)p)[i];
            lm = fmaxf(lm, fmaxf(fmaxf(v[j].x, v[j].y), fmaxf(v[j].z, v[j].w)));
        }
    }
    #pragma unroll
    for (int off = 32; off; off >>= 1) lm = fmaxf(lm, __shfl_xor(lm, off));
    if ((t & 63) == 0) red[t >> 6] = lm;
    __syncthreads();
    const float gm = fmaxf(fmaxf(red[0], red[1]), fmaxf(red[2], red[3]));

    float ls = 0.f;
    #pragma unroll
    for (int j = 0; j < 4; ++j) {
        int i = t + j * 256;
        if (i < 1000)
            ls += __expf(v[j].x - gm) + __expf(v[j].y - gm) +
                  __expf(v[j].z - gm) + __expf(v[j].w - gm);
    }
    #pragma unroll
    for (int off = 32; off; off >>= 1) ls += __shfl_xor(ls, off);
    __syncthreads();
    if ((t & 63) == 0) red[t >> 6] = ls;
    __syncthreads();
    const float sh = gm + logf(red[0] + red[1] + red[2] + red[3]);

    #pragma unroll
    for (int j = 0; j < 4; ++j) {
        int i = t + j * 256;
        if (i < 1000) {
            float4 o;
            o.x = v[j].x - sh; o.y = v[j].y - sh;
            o.z = v[j].z - sh; o.w = v[j].w - sh;
            ((float4*)(dout + b * NANS))[i] = o;
        }
    }
}

// ---------------------------------------------------------------------------
extern "C" void kernel_launch(void* const* d_in, const int* in_sizes, int n_in,
                              void* d_out, int out_size, void* d_ws, size_t ws_size,
                              hipStream_t stream)
{
    (void)in_sizes; (void)n_in; (void)out_size; (void)ws_size;
    const int*   he_q  = (const int*)  d_in[0];
    const int*   he_k  = (const int*)  d_in[1];
    const float* emb   = (const float*)d_in[2];
    const float* Wq    = (const float*)d_in[3];
    const float* bq    = (const float*)d_in[4];
    const float* Wk    = (const float*)d_in[5];
    const float* bk    = (const float*)d_in[6];
    const float* Watt  = (const float*)d_in[7];
    const float* batt  = (const float*)d_in[8];
    const float* Wout  = (const float*)d_in[9];
    const float* bout  = (const float*)d_in[10];
    const float* glove = (const float*)d_in[11];
    float* out = (float*)d_out;

    ushort* WTq    = (ushort*)d_ws;                  //    327,680 sh
    ushort* WTk    = WTq + 327680;                   //    327,680 sh
    ushort* emb_bf = WTk + 327680;                   //  6,400,000 sh  [v][320]
    ushort* hq_bf  = emb_bf + 6400000;               //  2,097,152 sh  [b][q][d]
    ushort* hk_bf  = hq_bf + 2097152;                // 16,777,216 sh  [b][k][d]
    ushort* hkT    = hk_bf + 16777216;               // 16,777,216 sh  [b][d][k]
    ushort* pool_bf= hkT + 16777216;                 //    524,288 sh  [b][g*H+d]
    ushort* woutT  = pool_bf + 524288;               //  2,621,440 sh  [320][8192]
    ushort* att    = woutT + 2621440;                //  4,194,304 sh
    float*  partial= (float*)(att + 4194304);        //  1,310,720 f32 [64][64][320]
    float*  outv   = partial + 1310720;              //     19,456 f32
    float*  sim    = outv + 19456;                   //    256,000 f32

    prep_emb<<<dim3(313), 256, 0, stream>>>(emb, emb_bf);
    prep_wt<<<dim3(16, 2), 256, 0, stream>>>(Wq, Wk, WTq, WTk);
    prep_woutT<<<dim3(128, 5), 256, 0, stream>>>(Wout, woutT);
    proj_big<0><<<dim3(16, 8), 256, 0, stream>>>(he_q, emb_bf, WTq, bq, hq_bf, nullptr);
    proj_big<1><<<dim3(128, 8), 256, 0, stream>>>(he_k, emb_bf, WTk, bk, hk_bf, hkT);
    attn_mfma<<<dim3(64, 8), 256, 0, stream>>>(hq_bf, hk_bf, Watt, batt, att);
    pooled_mfma<<<dim3(64, 8), 256, 0, stream>>>(att, hkT, hq_bf, pool_bf);
    outproj_mfma<<<dim3(64), 256, 0, stream>>>(pool_bf, woutT, partial);
    reduce_out_kernel<<<dim3(76), 256, 0, stream>>>(partial, bout, outv);
    sim_kernel<<<dim3(250), 256, 0, stream>>>(outv, glove, sim);
    lsm_kernel<<<dim3(64), 256, 0, stream>>>(sim, out);
}